// Round 11
// baseline (244.255 us; speedup 1.0000x reference)
//
#include <hip/hip_runtime.h>
#include <hip/hip_bf16.h>

#define NN 100000      // nodes
#define NE 3200000     // edges
#define NF 256         // features

typedef __attribute__((ext_vector_type(8))) __bf16 bf16x8;
typedef __attribute__((ext_vector_type(4))) float  f32x4;
typedef __attribute__((ext_vector_type(4))) int    i32x4;
typedef __attribute__((ext_vector_type(2))) int    i32x2;

// Table layout (per node, 256 B): byte p holds feature feat(p) = (p&15)*16 + (p>>4)
// (16x16 transpose). Gemm lane (ccol) packs its 16 features into bytes
// [ccol*16, ccol*16+16); spmm lane l's 4 bytes at 4l..4l+3 are features
// (l&3)*64 + 16b + (l>>2), b=0..3.

// ---- prep: W -> per-lane MFMA B-fragments (bf16) + permuted bias ----
__global__ __launch_bounds__(256) void prep_w(const float* __restrict__ w,
                                              __bf16* __restrict__ wfrag,
                                              const float* __restrict__ bias,
                                              float* __restrict__ bias_p) {
    if (blockIdx.x == 32) {          // permuted bias: bias_p[4l+b] = bias[F(l,b)]
        const int t = threadIdx.x;   // 0..255
        const int l = t >> 2, b = t & 3;
        bias_p[t] = bias[(l & 3) * 64 + 16 * b + (l >> 2)];
        return;
    }
    const int t = blockIdx.x * 256 + threadIdx.x;   // 8192 total
    const int lane = t & 63;
    const int nf   = (t >> 6) & 15;
    const int ks   = t >> 10;
    const int col  = nf * 16 + (lane & 15);
    const int k0   = ks * 32 + (lane >> 4) * 8;
    bf16x8 v;
#pragma unroll
    for (int j = 0; j < 8; ++j) v[j] = (__bf16)w[(k0 + j) * NF + col];
    reinterpret_cast<bf16x8*>(wfrag)[t] = v;
}

// ---- fused GEMM + i8 quantize ----
__global__ __launch_bounds__(320) void gemm_q(const float* __restrict__ x,
                                              const __bf16* __restrict__ wfrag,
                                              unsigned char* __restrict__ tab,
                                              float* __restrict__ scales) {
    __shared__ __align__(16) __bf16 As[80 * 72];   // row stride 144 B

    const int t    = threadIdx.x;
    const int wv   = t >> 6;
    const int lane = t & 63;
    const int row0 = blockIdx.x * 80;

    f32x4 acc[16];
#pragma unroll
    for (int nf = 0; nf < 16; ++nf) acc[nf] = (f32x4){0.f, 0.f, 0.f, 0.f};

    const int   srow = t >> 2;
    const int   sj   = (t & 3) * 8;
    const float* xp  = x + (size_t)(row0 + srow) * NF + sj;
    char* const  wr  = reinterpret_cast<char*>(As) + srow * 144 + sj * 2;

    const char* const rd =
        reinterpret_cast<const char*>(As) + (wv * 16 + (lane & 15)) * 144 + ((lane >> 4) << 4);

    const bf16x8* wf = reinterpret_cast<const bf16x8*>(wfrag);

    f32x4 s0 = __builtin_nontemporal_load(reinterpret_cast<const f32x4*>(xp));
    f32x4 s1 = __builtin_nontemporal_load(reinterpret_cast<const f32x4*>(xp + 4));

    for (int ks = 0; ks < 8; ++ks) {
        bf16x8 sb;
        sb[0] = (__bf16)s0.x; sb[1] = (__bf16)s0.y;
        sb[2] = (__bf16)s0.z; sb[3] = (__bf16)s0.w;
        sb[4] = (__bf16)s1.x; sb[5] = (__bf16)s1.y;
        sb[6] = (__bf16)s1.z; sb[7] = (__bf16)s1.w;
        *reinterpret_cast<bf16x8*>(wr) = sb;       // ds_write_b128
        __syncthreads();

        if (ks < 7) {
            s0 = __builtin_nontemporal_load(
                reinterpret_cast<const f32x4*>(xp + (ks + 1) * 32));
            s1 = __builtin_nontemporal_load(
                reinterpret_cast<const f32x4*>(xp + (ks + 1) * 32 + 4));
        }

        const bf16x8 af = *reinterpret_cast<const bf16x8*>(rd);  // ds_read_b128
#pragma unroll
        for (int nf = 0; nf < 16; ++nf) {
            const bf16x8 bfr = wf[(ks * 16 + nf) * 64 + lane];
            acc[nf] = __builtin_amdgcn_mfma_f32_16x16x32_bf16(af, bfr, acc[nf], 0, 0, 0);
        }
        __syncthreads();
    }

    // Epilogue: per-row absmax -> i8, packed 16 B/lane (transposed table layout).
    const int hi   = lane >> 4;
    const int ccol = lane & 15;

    float m[4];
#pragma unroll
    for (int r = 0; r < 4; ++r) {
        float mm = 0.f;
#pragma unroll
        for (int nf = 0; nf < 16; ++nf) mm = fmaxf(mm, fabsf(acc[nf][r]));
        m[r] = mm;
    }
#pragma unroll
    for (int w = 1; w < 16; w <<= 1) {
#pragma unroll
        for (int r = 0; r < 4; ++r) m[r] = fmaxf(m[r], __shfl_xor(m[r], w, 64));
    }

#pragma unroll
    for (int r = 0; r < 4; ++r) {
        const int   node = row0 + wv * 16 + hi * 4 + r;
        const float isc  = 127.0f / fmaxf(m[r], 1e-30f);
        uint4 pk = {0u, 0u, 0u, 0u};
        unsigned int* pw = reinterpret_cast<unsigned int*>(&pk);
#pragma unroll
        for (int nf = 0; nf < 16; ++nf) {
            const int q = (int)rintf(acc[nf][r] * isc);
            pw[nf >> 2] |= ((unsigned int)(q & 0xff)) << ((nf & 3) * 8);
        }
        *reinterpret_cast<uint4*>(tab + (size_t)node * 256 + ccol * 16) = pk;
        if (ccol == 0) scales[node] = m[r] * (1.0f / 127.0f);
    }
}

// ---- CSR row pointers from sorted edge_row (int32) ----
__global__ void build_rowptr(const int* __restrict__ erow,
                             int* __restrict__ rowptr) {
    int e = blockIdx.x * blockDim.x + threadIdx.x;
    if (e >= NE) return;
    int r    = erow[e];
    int prev = (e == 0) ? -1 : erow[e - 1];
    for (int q = prev + 1; q <= r; ++q) rowptr[q] = e;
    if (e == NE - 1) {
        for (int q = r + 1; q <= NN; ++q) rowptr[q] = NE;
    }
}

// ---- prepass: pairs[e] = (ecol[e], eval[e] * scales[ecol[e]]), 8 edges/thread ----
__global__ __launch_bounds__(256) void prep_pairs(const int* __restrict__ ecol,
                                                  const float* __restrict__ eval,
                                                  const float* __restrict__ scales,
                                                  i32x2* __restrict__ pairs) {
    const int t = blockIdx.x * 256 + threadIdx.x;     // 400,000 active threads
    if (t >= NE / 8) return;
    const int base = t * 8;

    const i32x4  c0 = __builtin_nontemporal_load(reinterpret_cast<const i32x4*>(ecol + base));
    const i32x4  c1 = __builtin_nontemporal_load(reinterpret_cast<const i32x4*>(ecol + base + 4));
    const f32x4  v0 = __builtin_nontemporal_load(reinterpret_cast<const f32x4*>(eval + base));
    const f32x4  v1 = __builtin_nontemporal_load(reinterpret_cast<const f32x4*>(eval + base + 4));

    // 8 independent scale gathers (L2-hot, 400 KB table)
    const float s0 = scales[c0.x], s1 = scales[c0.y], s2 = scales[c0.z], s3 = scales[c0.w];
    const float s4 = scales[c1.x], s5 = scales[c1.y], s6 = scales[c1.z], s7 = scales[c1.w];

    i32x4 p01, p23, p45, p67;
    p01.x = c0.x; p01.y = __float_as_int(v0.x * s0);
    p01.z = c0.y; p01.w = __float_as_int(v0.y * s1);
    p23.x = c0.z; p23.y = __float_as_int(v0.z * s2);
    p23.z = c0.w; p23.w = __float_as_int(v0.w * s3);
    p45.x = c1.x; p45.y = __float_as_int(v1.x * s4);
    p45.z = c1.y; p45.w = __float_as_int(v1.y * s5);
    p67.x = c1.z; p67.y = __float_as_int(v1.z * s6);
    p67.z = c1.w; p67.w = __float_as_int(v1.w * s7);

    i32x4* pp = reinterpret_cast<i32x4*>(pairs + base);
    __builtin_nontemporal_store(p01, pp);
    __builtin_nontemporal_store(p23, pp + 1);
    __builtin_nontemporal_store(p45, pp + 2);
    __builtin_nontemporal_store(p67, pp + 3);
}

// ---- spmm (i8 permuted table): one wave per row; 2 edges per iteration ----
__global__ __launch_bounds__(256) void spmm_i8(const unsigned int* __restrict__ tab32,
                                               const int* __restrict__ rowptr,
                                               const i32x2* __restrict__ pairs,
                                               const float* __restrict__ bias_p,
                                               float* __restrict__ out) {
    const int wave = threadIdx.x >> 6;
    const int lane = threadIdx.x & 63;
    const int row  = blockIdx.x * 4 + wave;

    const int s = rowptr[row];
    const int e = rowptr[row + 1];

    float a0 = 0.f, a1 = 0.f, a2 = 0.f, a3 = 0.f;

#define ACC1(c, vbits)                                                 \
    do {                                                               \
        const float v = __int_as_float(vbits);                         \
        const unsigned int g = tab32[((unsigned)(c) << 6) + lane];     \
        a0 = fmaf(v, (float)(int)(signed char)(g      ), a0);          \
        a1 = fmaf(v, (float)(int)(signed char)(g >> 8 ), a1);          \
        a2 = fmaf(v, (float)(int)(signed char)(g >> 16), a2);          \
        a3 = fmaf(v, (float)(int)(signed char)(g >> 24), a3);          \
    } while (0)

    int i = s;
    if ((i & 1) && i < e) {                    // align to even index (16 B)
        const i32x2 p = pairs[i];
        ACC1(p.x, p.y);
        ++i;
    }
#pragma unroll 2
    for (; i + 2 <= e; i += 2) {
        const i32x4 p = *reinterpret_cast<const i32x4*>(pairs + i);  // 16 B, one line
        ACC1(p.x, p.y);
        ACC1(p.z, p.w);
    }
    if (i < e) {
        const i32x2 p = pairs[i];
        ACC1(p.x, p.y);
    }
#undef ACC1

    // lane's features: F(b) = (lane&3)*64 + 16b + (lane>>2); bias pre-permuted
    const f32x4 bp = *reinterpret_cast<const f32x4*>(bias_p + lane * 4);
    float* op = out + (size_t)row * NF + (lane & 3) * 64 + (lane >> 2);
    __builtin_nontemporal_store(a0 + bp.x, op);
    __builtin_nontemporal_store(a1 + bp.y, op + 16);
    __builtin_nontemporal_store(a2 + bp.z, op + 32);
    __builtin_nontemporal_store(a3 + bp.w, op + 48);
}

extern "C" void kernel_launch(void* const* d_in, const int* in_sizes, int n_in,
                              void* d_out, int out_size, void* d_ws, size_t ws_size,
                              hipStream_t stream) {
    const float* x    = (const float*)d_in[0];
    const int*   erow = (const int*)d_in[1];
    const int*   ecol = (const int*)d_in[2];
    const float* eval = (const float*)d_in[3];
    const float* w    = (const float*)d_in[4];
    const float* bias = (const float*)d_in[5];
    float*       out  = (float*)d_out;

    unsigned char* tab    = (unsigned char*)d_ws;                      // 25,600,000 B
    i32x2*         pairs  = (i32x2*)((char*)d_ws + 25600000);          // 25,600,000 B
    int*           rowptr = (int*)((char*)d_ws + 51200000);            //    400,004 B
    __bf16*        wfrag  = (__bf16*)((char*)d_ws + 51600016);         //    131,072 B
    float*         scales = (float*)((char*)d_ws + 51731088);          //    400,000 B
    float*         bias_p = (float*)((char*)d_ws + 52131088);          //      1,024 B

    prep_w<<<33, 256, 0, stream>>>(w, wfrag, bias, bias_p);
    build_rowptr<<<(NE + 255) / 256, 256, 0, stream>>>(erow, rowptr);
    gemm_q<<<NN / 80, 320, 0, stream>>>(x, wfrag, tab, scales);
    prep_pairs<<<(NE / 8 + 255) / 256, 256, 0, stream>>>(ecol, eval, scales, pairs);
    spmm_i8<<<NN / 4, 256, 0, stream>>>(
        reinterpret_cast<const unsigned int*>(tab), rowptr, pairs, bias_p, out);
}

// Round 12
// 196.417 us; speedup vs baseline: 1.2436x; 1.2436x over previous
//
#include <hip/hip_runtime.h>
#include <hip/hip_bf16.h>

#define NN 100000      // nodes
#define NE 3200000     // edges
#define NF 256         // features
#define CHUNK 512      // staged edges per block iteration

typedef __attribute__((ext_vector_type(8))) __bf16 bf16x8;
typedef __attribute__((ext_vector_type(4))) float  f32x4;

// Table layout (per node, 256 B): byte p holds feature feat(p) = (p&15)*16 + (p>>4)
// (16x16 transpose). Gemm lane (ccol) packs its 16 features into bytes
// [ccol*16, ccol*16+16); spmm lane l's 4 bytes at 4l..4l+3 are features
// (l&3)*64 + 16b + (l>>2), b=0..3.

// ---- prep: W -> per-lane MFMA B-fragments (bf16) + permuted bias ----
__global__ __launch_bounds__(256) void prep_w(const float* __restrict__ w,
                                              __bf16* __restrict__ wfrag,
                                              const float* __restrict__ bias,
                                              float* __restrict__ bias_p) {
    if (blockIdx.x == 32) {          // permuted bias: bias_p[4l+b] = bias[F(l,b)]
        const int t = threadIdx.x;   // 0..255
        const int l = t >> 2, b = t & 3;
        bias_p[t] = bias[(l & 3) * 64 + 16 * b + (l >> 2)];
        return;
    }
    const int t = blockIdx.x * 256 + threadIdx.x;   // 8192 total
    const int lane = t & 63;
    const int nf   = (t >> 6) & 15;
    const int ks   = t >> 10;
    const int col  = nf * 16 + (lane & 15);
    const int k0   = ks * 32 + (lane >> 4) * 8;
    bf16x8 v;
#pragma unroll
    for (int j = 0; j < 8; ++j) v[j] = (__bf16)w[(k0 + j) * NF + col];
    reinterpret_cast<bf16x8*>(wfrag)[t] = v;
}

// ---- fused GEMM + i8 quantize ----
__global__ __launch_bounds__(320) void gemm_q(const float* __restrict__ x,
                                              const __bf16* __restrict__ wfrag,
                                              unsigned char* __restrict__ tab,
                                              float* __restrict__ scales) {
    __shared__ __align__(16) __bf16 As[80 * 72];   // row stride 144 B

    const int t    = threadIdx.x;
    const int wv   = t >> 6;
    const int lane = t & 63;
    const int row0 = blockIdx.x * 80;

    f32x4 acc[16];
#pragma unroll
    for (int nf = 0; nf < 16; ++nf) acc[nf] = (f32x4){0.f, 0.f, 0.f, 0.f};

    const int   srow = t >> 2;
    const int   sj   = (t & 3) * 8;
    const float* xp  = x + (size_t)(row0 + srow) * NF + sj;
    char* const  wr  = reinterpret_cast<char*>(As) + srow * 144 + sj * 2;

    const char* const rd =
        reinterpret_cast<const char*>(As) + (wv * 16 + (lane & 15)) * 144 + ((lane >> 4) << 4);

    const bf16x8* wf = reinterpret_cast<const bf16x8*>(wfrag);

    f32x4 s0 = __builtin_nontemporal_load(reinterpret_cast<const f32x4*>(xp));
    f32x4 s1 = __builtin_nontemporal_load(reinterpret_cast<const f32x4*>(xp + 4));

    for (int ks = 0; ks < 8; ++ks) {
        bf16x8 sb;
        sb[0] = (__bf16)s0.x; sb[1] = (__bf16)s0.y;
        sb[2] = (__bf16)s0.z; sb[3] = (__bf16)s0.w;
        sb[4] = (__bf16)s1.x; sb[5] = (__bf16)s1.y;
        sb[6] = (__bf16)s1.z; sb[7] = (__bf16)s1.w;
        *reinterpret_cast<bf16x8*>(wr) = sb;       // ds_write_b128
        __syncthreads();

        if (ks < 7) {
            s0 = __builtin_nontemporal_load(
                reinterpret_cast<const f32x4*>(xp + (ks + 1) * 32));
            s1 = __builtin_nontemporal_load(
                reinterpret_cast<const f32x4*>(xp + (ks + 1) * 32 + 4));
        }

        const bf16x8 af = *reinterpret_cast<const bf16x8*>(rd);  // ds_read_b128
#pragma unroll
        for (int nf = 0; nf < 16; ++nf) {
            const bf16x8 bfr = wf[(ks * 16 + nf) * 64 + lane];
            acc[nf] = __builtin_amdgcn_mfma_f32_16x16x32_bf16(af, bfr, acc[nf], 0, 0, 0);
        }
        __syncthreads();
    }

    // Epilogue: per-row absmax -> i8, packed 16 B/lane (transposed table layout).
    const int hi   = lane >> 4;
    const int ccol = lane & 15;

    float m[4];
#pragma unroll
    for (int r = 0; r < 4; ++r) {
        float mm = 0.f;
#pragma unroll
        for (int nf = 0; nf < 16; ++nf) mm = fmaxf(mm, fabsf(acc[nf][r]));
        m[r] = mm;
    }
#pragma unroll
    for (int w = 1; w < 16; w <<= 1) {
#pragma unroll
        for (int r = 0; r < 4; ++r) m[r] = fmaxf(m[r], __shfl_xor(m[r], w, 64));
    }

#pragma unroll
    for (int r = 0; r < 4; ++r) {
        const int   node = row0 + wv * 16 + hi * 4 + r;
        const float isc  = 127.0f / fmaxf(m[r], 1e-30f);
        uint4 pk = {0u, 0u, 0u, 0u};
        unsigned int* pw = reinterpret_cast<unsigned int*>(&pk);
#pragma unroll
        for (int nf = 0; nf < 16; ++nf) {
            const int q = (int)rintf(acc[nf][r] * isc);
            pw[nf >> 2] |= ((unsigned int)(q & 0xff)) << ((nf & 3) * 8);
        }
        *reinterpret_cast<uint4*>(tab + (size_t)node * 256 + ccol * 16) = pk;
        if (ccol == 0) scales[node] = m[r] * (1.0f / 127.0f);
    }
}

// ---- CSR row pointers from sorted edge_row (int32) ----
__global__ void build_rowptr(const int* __restrict__ erow,
                             int* __restrict__ rowptr) {
    int e = blockIdx.x * blockDim.x + threadIdx.x;
    if (e >= NE) return;
    int r    = erow[e];
    int prev = (e == 0) ? -1 : erow[e - 1];
    for (int q = prev + 1; q <= r; ++q) rowptr[q] = e;
    if (e == NE - 1) {
        for (int q = r + 1; q <= NN; ++q) rowptr[q] = NE;
    }
}

// ---- spmm fused: LDS-staged (c, v*scale) stream + i8 table gather ----
// Block = 4 rows (one wave each). Rows sorted -> block's edges are the
// contiguous span [rowptr[4b], rowptr[4b+4]). Stage <=CHUNK edges at a time:
// coalesced ecol/eval + L2-hot scales gather, fold v*s, 8 B to LDS. Inner
// loop: ds_read_b64 broadcast + 1 table gather + 4 fma per edge.
__global__ __launch_bounds__(256) void spmm_f(const unsigned int* __restrict__ tab32,
                                              const int* __restrict__ rowptr,
                                              const int* __restrict__ ecol,
                                              const float* __restrict__ eval,
                                              const float* __restrict__ scales,
                                              const float* __restrict__ bias_p,
                                              float* __restrict__ out) {
    __shared__ int2 buf[CHUNK];

    const int wave = threadIdx.x >> 6;
    const int lane = threadIdx.x & 63;
    const int row  = blockIdx.x * 4 + wave;

    const int bs   = rowptr[blockIdx.x * 4];
    const int bend = rowptr[blockIdx.x * 4 + 4];
    const int rs   = rowptr[row];
    const int re   = rowptr[row + 1];

    float a0 = 0.f, a1 = 0.f, a2 = 0.f, a3 = 0.f;

    for (int cs = bs; cs < bend; cs += CHUNK) {
        const int cnt = min(CHUNK, bend - cs);
        if (cs != bs) __syncthreads();             // protect buf reuse
        for (int j = threadIdx.x; j < cnt; j += 256) {
            const int   c = ecol[cs + j];          // coalesced
            const float v = eval[cs + j];          // coalesced
            buf[j] = make_int2(c, __float_as_int(v * scales[c]));  // scales L2-hot
        }
        __syncthreads();

        const int lo = max(rs, cs);
        const int hi = min(re, cs + cnt);
#pragma unroll 4
        for (int i = lo; i < hi; ++i) {
            const int2  p = buf[i - cs];           // ds_read_b64 broadcast
            const float v = __int_as_float(p.y);
            const unsigned int g = tab32[((unsigned)p.x << 6) + lane];
            a0 = fmaf(v, (float)(int)(signed char)(g      ), a0);
            a1 = fmaf(v, (float)(int)(signed char)(g >> 8 ), a1);
            a2 = fmaf(v, (float)(int)(signed char)(g >> 16), a2);
            a3 = fmaf(v, (float)(int)(signed char)(g >> 24), a3);
        }
    }

    // lane's features: F(b) = (lane&3)*64 + 16b + (lane>>2); bias pre-permuted
    const f32x4 bp = *reinterpret_cast<const f32x4*>(bias_p + lane * 4);
    float* op = out + (size_t)row * NF + (lane & 3) * 64 + (lane >> 2);
    __builtin_nontemporal_store(a0 + bp.x, op);
    __builtin_nontemporal_store(a1 + bp.y, op + 16);
    __builtin_nontemporal_store(a2 + bp.z, op + 32);
    __builtin_nontemporal_store(a3 + bp.w, op + 48);
}

extern "C" void kernel_launch(void* const* d_in, const int* in_sizes, int n_in,
                              void* d_out, int out_size, void* d_ws, size_t ws_size,
                              hipStream_t stream) {
    const float* x    = (const float*)d_in[0];
    const int*   erow = (const int*)d_in[1];
    const int*   ecol = (const int*)d_in[2];
    const float* eval = (const float*)d_in[3];
    const float* w    = (const float*)d_in[4];
    const float* bias = (const float*)d_in[5];
    float*       out  = (float*)d_out;

    unsigned char* tab    = (unsigned char*)d_ws;                      // 25,600,000 B
    int*           rowptr = (int*)((char*)d_ws + 25600000);            //    400,004 B
    __bf16*        wfrag  = (__bf16*)((char*)d_ws + 26000016);         //    131,072 B
    float*         scales = (float*)((char*)d_ws + 26131088);          //    400,000 B
    float*         bias_p = (float*)((char*)d_ws + 26531088);          //      1,024 B

    prep_w<<<33, 256, 0, stream>>>(w, wfrag, bias, bias_p);
    build_rowptr<<<(NE + 255) / 256, 256, 0, stream>>>(erow, rowptr);
    gemm_q<<<NN / 80, 320, 0, stream>>>(x, wfrag, tab, scales);
    spmm_f<<<NN / 4, 256, 0, stream>>>(
        reinterpret_cast<const unsigned int*>(tab), rowptr, ecol, eval, scales,
        bias_p, out);
}